// Round 8
// baseline (697.103 us; speedup 1.0000x reference)
//
#include <hip/hip_runtime.h>

#define CCH 48          // channels
#define RREP 8          // deg histogram replicas
#define SHIFT 7         // log2(nodes per bucket)
#define BNODES (1 << SHIFT)   // 128 nodes/bucket; NB = ceil(N/128) <= 1024 for N <= 131072
#define EPB 4096        // edges per binning block (256 thr x 16)
#define TILE 2048       // scan elements per block
#define SBT 256         // scan block threads

// Row-degree histogram (replicated to spread lines). Only remaining global atomics.
__global__ void histo_deg(const int* __restrict__ row, int* __restrict__ degR,
                          int N, int E) {
    int e = blockIdx.x * blockDim.x + threadIdx.x;
    if (e >= E) return;
    long long r = blockIdx.x & (RREP - 1);
    atomicAdd(&degR[r * N + row[e]], 1);
}

// dis[n] = rsqrt(sum_r degR[r*N+n] + 1)
__global__ void reduce_dis(const int* __restrict__ degR, float* __restrict__ dis, int N) {
    int n = blockIdx.x * blockDim.x + threadIdx.x;
    if (n >= N) return;
    int s = 0;
#pragma unroll
    for (int r = 0; r < RREP; ++r) s += degR[(long long)r * N + n];
    dis[n] = rsqrtf((float)s + 1.0f);
}

// Level-1 pass A: per-block histogram of col buckets -> table[b*NB1 + blk].
__global__ void __launch_bounds__(256) bin_count(const int* __restrict__ col,
                                                 int* __restrict__ table,
                                                 int E, int NB, int NB1) {
    __shared__ int hist[1024];
    int tid = threadIdx.x, blk = blockIdx.x;
    for (int b = tid; b < NB; b += 256) hist[b] = 0;
    __syncthreads();
#pragma unroll
    for (int k = 0; k < 16; ++k) {
        int e = blk * EPB + k * 256 + tid;
        if (e < E) atomicAdd(&hist[col[e] >> SHIFT], 1);
    }
    __syncthreads();
    for (int b = tid; b < NB; b += 256) table[(long long)b * NB1 + blk] = hist[b];
}

// Generic 3-pass exclusive scan over table[M] -> scanOut[M] (+scanOut[M]=E).
__global__ void __launch_bounds__(SBT) scan_partial(const int* __restrict__ a,
                                                    int* __restrict__ bsum, int M) {
    __shared__ int sm[SBT];
    int b = blockIdx.x, tid = threadIdx.x;
    int base = b * TILE + tid * 8;
    int s = 0;
#pragma unroll
    for (int k = 0; k < 8; ++k) { int i = base + k; s += (i < M) ? a[i] : 0; }
    sm[tid] = s;
    __syncthreads();
    for (int off = SBT / 2; off > 0; off >>= 1) {
        if (tid < off) sm[tid] += sm[tid + off];
        __syncthreads();
    }
    if (tid == 0) bsum[b] = sm[0];
}

__global__ void __launch_bounds__(1024) scan_block(const int* __restrict__ bsum,
                                                   int* __restrict__ boff,
                                                   int* __restrict__ scanOut,
                                                   int B, int M, int E) {
    __shared__ int sm[1024];
    int tid = threadIdx.x;
    int v = (tid < B) ? bsum[tid] : 0;
    sm[tid] = v;
    __syncthreads();
    for (int off = 1; off < 1024; off <<= 1) {
        int t = (tid >= off) ? sm[tid - off] : 0;
        __syncthreads();
        sm[tid] += t;
        __syncthreads();
    }
    if (tid < B) boff[tid] = sm[tid] - v;
    if (tid == 0) scanOut[M] = E;  // sentinel
}

__global__ void __launch_bounds__(SBT) scan_final(const int* __restrict__ a,
                                                  const int* __restrict__ boff,
                                                  int* __restrict__ scanOut, int M) {
    __shared__ int sm[SBT];
    int b = blockIdx.x, tid = threadIdx.x;
    int base = b * TILE + tid * 8;
    int v[8];
    int s = 0;
#pragma unroll
    for (int k = 0; k < 8; ++k) { int i = base + k; v[k] = (i < M) ? a[i] : 0; s += v[k]; }
    sm[tid] = s;
    __syncthreads();
    for (int off = 1; off < SBT; off <<= 1) {
        int t = (tid >= off) ? sm[tid - off] : 0;
        __syncthreads();
        sm[tid] += t;
        __syncthreads();
    }
    int run = boff[b] + sm[tid] - s;
#pragma unroll
    for (int k = 0; k < 8; ++k) {
        int i = base + k;
        if (i < M) scanOut[i] = run;
        run += v[k];
    }
}

// Level-1 pass B: deterministic scatter into bucket-grouped order.
// Packed u64: [w:fp32 | colLow7<<17 | row:17b]. LDS atomics only.
__global__ void __launch_bounds__(256) bin_scatter(const int* __restrict__ row,
                                                   const int* __restrict__ col,
                                                   const float* __restrict__ dis,
                                                   const int* __restrict__ scanOut,
                                                   unsigned long long* __restrict__ binned,
                                                   int E, int NB, int NB1) {
    __shared__ int cur[1024];
    int tid = threadIdx.x, blk = blockIdx.x;
    for (int b = tid; b < NB; b += 256) cur[b] = scanOut[(long long)b * NB1 + blk];
    __syncthreads();
#pragma unroll
    for (int k = 0; k < 16; ++k) {
        int e = blk * EPB + k * 256 + tid;
        if (e < E) {
            int rw = row[e];
            int cl = col[e];
            int b = cl >> SHIFT;
            int pos = atomicAdd(&cur[b], 1);
            unsigned long long pk =
                (unsigned int)(rw | ((cl & (BNODES - 1)) << 17));
            pk |= ((unsigned long long)(unsigned int)__float_as_int(dis[rw])) << 32;
            binned[pos] = pk;
        }
    }
}

// One block per bucket: LDS fp32 accumulator, stream edges, fused write-out.
// out[n,c] = dis[n]*( sum_e w_e*label[src_e,c] + dis[n]*label[n,c] )
__global__ void __launch_bounds__(256) bucket_gather(const float* __restrict__ label,
                                                     const unsigned long long* __restrict__ binned,
                                                     const int* __restrict__ scanOut,
                                                     const float* __restrict__ dis,
                                                     float* __restrict__ out,
                                                     int N, int NB1) {
    __shared__ float acc[BNODES * CCH];  // 128*48*4 = 24.6 KB
    int tid = threadIdx.x, b = blockIdx.x;
    for (int j = tid; j < BNODES * CCH; j += 256) acc[j] = 0.0f;
    __syncthreads();

    int beg = scanOut[(long long)b * NB1];
    int end = scanOut[(long long)(b + 1) * NB1];  // b=NB-1 hits sentinel = E

    int g = tid >> 4;          // 16 edge-groups per block
    int l3 = (tid & 15) * 3;   // 3 channels per lane
    for (int i = beg + g; i < end; i += 16) {
        unsigned long long pk = binned[i];
        int low = (int)pk;
        int src = low & 0x1FFFF;
        int cl  = (low >> 17) & (BNODES - 1);
        float w = __int_as_float((int)(pk >> 32));
        const float* p = label + (long long)src * CCH + l3;
        float* a = &acc[cl * CCH + l3];
        atomicAdd(a,     w * p[0]);
        atomicAdd(a + 1, w * p[1]);
        atomicAdd(a + 2, w * p[2]);
    }
    __syncthreads();

    int n0 = b << SHIFT;
    for (int j = tid; j < BNODES * CCH; j += 256) {
        int ln = j / CCH;
        int c  = j - ln * CCH;
        int n  = n0 + ln;
        if (n < N) {
            float dn = dis[n];
            long long idx = (long long)n * CCH + c;
            out[idx] = dn * (acc[j] + dn * label[idx]);
        }
    }
}

extern "C" void kernel_launch(void* const* d_in, const int* in_sizes, int n_in,
                              void* d_out, int out_size, void* d_ws, size_t ws_size,
                              hipStream_t stream) {
    const float* label = (const float*)d_in[0];  // fp32 (N,48)
    const int* ei = (const int*)d_in[1];         // int32, (2,E) flat

    const int NC = in_sizes[0];  // N * 48
    const int N  = NC / CCH;
    const int E  = in_sizes[1] / 2;
    const int* row = ei;
    const int* col = ei + E;

    const int NB  = (N + BNODES - 1) >> SHIFT;       // 782 buckets
    const int NB1 = (E + EPB - 1) / EPB;             // 391 binning blocks
    const int M   = NB * NB1;                        // scan length ~306K
    const int B   = (M + TILE - 1) / TILE;           // scan blocks ~150

    // ws layout: [binned: E u64][degR: RREP*N i32][dis: N f32]
    //            [table: M i32][scanOut: M+1 i32][bsum: B][boff: B]
    unsigned long long* binned = (unsigned long long*)d_ws;
    int* degR = (int*)(binned + E);
    float* dis = (float*)(degR + (long long)RREP * N);
    int* table = (int*)(dis + N);
    int* scanOut = table + M;
    int* bsum = scanOut + (M + 1);
    int* boff = bsum + B;

    // Zero degR only. ws poisoned 0xAA before every call; all else fully written.
    hipMemsetAsync(degR, 0, (size_t)RREP * N * sizeof(int), stream);

    histo_deg<<<(E + 255) / 256, 256, 0, stream>>>(row, degR, N, E);
    reduce_dis<<<(N + 255) / 256, 256, 0, stream>>>(degR, dis, N);

    bin_count<<<NB1, 256, 0, stream>>>(col, table, E, NB, NB1);
    scan_partial<<<B, SBT, 0, stream>>>(table, bsum, M);
    scan_block<<<1, 1024, 0, stream>>>(bsum, boff, scanOut, B, M, E);
    scan_final<<<B, SBT, 0, stream>>>(table, boff, scanOut, M);

    bin_scatter<<<NB1, 256, 0, stream>>>(row, col, dis, scanOut, binned, E, NB, NB1);

    bucket_gather<<<NB, 256, 0, stream>>>(label, binned, scanOut, dis,
                                          (float*)d_out, N, NB1);
}

// Round 9
// 615.819 us; speedup vs baseline: 1.1320x; 1.1320x over previous
//
#include <hip/hip_runtime.h>

#define CCH 48          // channels
#define RREP 16         // deg histogram replicas
#define SHIFT 5         // log2(nodes per bucket)
#define BNODES (1 << SHIFT)   // 32 nodes/bucket
#define MAXNB 4096      // supports N <= 131072
#define EPB 4096        // edges per binning block (256 thr x 16)
#define TILE 2048       // scan elements per block
#define SBT 256         // scan block threads

// Row-degree histogram (replicated to spread lines). Only global atomics left.
__global__ void histo_deg(const int* __restrict__ row, int* __restrict__ degR,
                          int N, int E) {
    int e = blockIdx.x * blockDim.x + threadIdx.x;
    if (e >= E) return;
    long long r = blockIdx.x & (RREP - 1);
    atomicAdd(&degR[r * N + row[e]], 1);
}

// dis[n] = rsqrt(sum_r degR[r*N+n] + 1)
__global__ void reduce_dis(const int* __restrict__ degR, float* __restrict__ dis, int N) {
    int n = blockIdx.x * blockDim.x + threadIdx.x;
    if (n >= N) return;
    int s = 0;
#pragma unroll
    for (int r = 0; r < RREP; ++r) s += degR[(long long)r * N + n];
    dis[n] = rsqrtf((float)s + 1.0f);
}

// Pass A: per-block histogram of col buckets -> table[b*NB1 + blk].
__global__ void __launch_bounds__(256) bin_count(const int* __restrict__ col,
                                                 int* __restrict__ table,
                                                 int E, int NB, int NB1) {
    __shared__ int hist[MAXNB];
    int tid = threadIdx.x, blk = blockIdx.x;
    for (int b = tid; b < NB; b += 256) hist[b] = 0;
    __syncthreads();
#pragma unroll
    for (int k = 0; k < 16; ++k) {
        int e = blk * EPB + k * 256 + tid;
        if (e < E) atomicAdd(&hist[col[e] >> SHIFT], 1);
    }
    __syncthreads();
    for (int b = tid; b < NB; b += 256) table[(long long)b * NB1 + blk] = hist[b];
}

// Generic 3-pass exclusive scan over table[M] -> scanOut[M] (+scanOut[M]=E).
__global__ void __launch_bounds__(SBT) scan_partial(const int* __restrict__ a,
                                                    int* __restrict__ bsum, int M) {
    __shared__ int sm[SBT];
    int b = blockIdx.x, tid = threadIdx.x;
    int base = b * TILE + tid * 8;
    int s = 0;
#pragma unroll
    for (int k = 0; k < 8; ++k) { int i = base + k; s += (i < M) ? a[i] : 0; }
    sm[tid] = s;
    __syncthreads();
    for (int off = SBT / 2; off > 0; off >>= 1) {
        if (tid < off) sm[tid] += sm[tid + off];
        __syncthreads();
    }
    if (tid == 0) bsum[b] = sm[0];
}

__global__ void __launch_bounds__(1024) scan_block(const int* __restrict__ bsum,
                                                   int* __restrict__ boff,
                                                   int* __restrict__ scanOut,
                                                   int B, int M, int E) {
    __shared__ int sm[1024];
    int tid = threadIdx.x;
    int v = (tid < B) ? bsum[tid] : 0;
    sm[tid] = v;
    __syncthreads();
    for (int off = 1; off < 1024; off <<= 1) {
        int t = (tid >= off) ? sm[tid - off] : 0;
        __syncthreads();
        sm[tid] += t;
        __syncthreads();
    }
    if (tid < B) boff[tid] = sm[tid] - v;
    if (tid == 0) scanOut[M] = E;  // sentinel
}

__global__ void __launch_bounds__(SBT) scan_final(const int* __restrict__ a,
                                                  const int* __restrict__ boff,
                                                  int* __restrict__ scanOut, int M) {
    __shared__ int sm[SBT];
    int b = blockIdx.x, tid = threadIdx.x;
    int base = b * TILE + tid * 8;
    int v[8];
    int s = 0;
#pragma unroll
    for (int k = 0; k < 8; ++k) { int i = base + k; v[k] = (i < M) ? a[i] : 0; s += v[k]; }
    sm[tid] = s;
    __syncthreads();
    for (int off = 1; off < SBT; off <<= 1) {
        int t = (tid >= off) ? sm[tid - off] : 0;
        __syncthreads();
        sm[tid] += t;
        __syncthreads();
    }
    int run = boff[b] + sm[tid] - s;
#pragma unroll
    for (int k = 0; k < 8; ++k) {
        int i = base + k;
        if (i < M) scanOut[i] = run;
        run += v[k];
    }
}

// Pass B: deterministic scatter into bucket-grouped order.
// Packed u64: [w:fp32 | colLow5<<17 | row:17b]. LDS atomics only.
__global__ void __launch_bounds__(256) bin_scatter(const int* __restrict__ row,
                                                   const int* __restrict__ col,
                                                   const float* __restrict__ dis,
                                                   const int* __restrict__ scanOut,
                                                   unsigned long long* __restrict__ binned,
                                                   int E, int NB, int NB1) {
    __shared__ int cur[MAXNB];
    int tid = threadIdx.x, blk = blockIdx.x;
    for (int b = tid; b < NB; b += 256) cur[b] = scanOut[(long long)b * NB1 + blk];
    __syncthreads();
#pragma unroll
    for (int k = 0; k < 16; ++k) {
        int e = blk * EPB + k * 256 + tid;
        if (e < E) {
            int rw = row[e];
            int cl = col[e];
            int b = cl >> SHIFT;
            int pos = atomicAdd(&cur[b], 1);
            unsigned long long pk =
                (unsigned int)(rw | ((cl & (BNODES - 1)) << 17));
            pk |= ((unsigned long long)(unsigned int)__float_as_int(dis[rw])) << 32;
            binned[pos] = pk;
        }
    }
}

// One block per bucket: 6 KB LDS accumulator, 4x-unrolled pipelined edge stream.
// out[n,c] = dis[n]*( sum_e w_e*label[src_e,c] + dis[n]*label[n,c] )
__global__ void __launch_bounds__(256) bucket_gather(const float* __restrict__ label,
                                                     const unsigned long long* __restrict__ binned,
                                                     const int* __restrict__ scanOut,
                                                     const float* __restrict__ dis,
                                                     float* __restrict__ out,
                                                     int N, int NB1) {
    __shared__ float acc[BNODES * CCH];  // 32*48*4 = 6 KB
    int tid = threadIdx.x, b = blockIdx.x;
    for (int j = tid; j < BNODES * CCH; j += 256) acc[j] = 0.0f;
    __syncthreads();

    int beg = scanOut[(long long)b * NB1];
    int end = scanOut[(long long)(b + 1) * NB1];  // last bucket hits sentinel = E

    int g = tid >> 4;          // 16 edge-groups per block
    int l3 = (tid & 15) * 3;   // 3 channels per lane

    int i = beg + g;
    // 4-deep pipelined main loop: 4 independent random label loads in flight.
    for (; i + 48 < end; i += 64) {
        unsigned long long pk0 = binned[i];
        unsigned long long pk1 = binned[i + 16];
        unsigned long long pk2 = binned[i + 32];
        unsigned long long pk3 = binned[i + 48];
        int lo0 = (int)pk0, lo1 = (int)pk1, lo2 = (int)pk2, lo3 = (int)pk3;
        const float* p0 = label + (long long)(lo0 & 0x1FFFF) * CCH + l3;
        const float* p1 = label + (long long)(lo1 & 0x1FFFF) * CCH + l3;
        const float* p2 = label + (long long)(lo2 & 0x1FFFF) * CCH + l3;
        const float* p3 = label + (long long)(lo3 & 0x1FFFF) * CCH + l3;
        float x0 = p0[0], y0 = p0[1], z0 = p0[2];
        float x1 = p1[0], y1 = p1[1], z1 = p1[2];
        float x2 = p2[0], y2 = p2[1], z2 = p2[2];
        float x3 = p3[0], y3 = p3[1], z3 = p3[2];
        float w0 = __int_as_float((int)(pk0 >> 32));
        float w1 = __int_as_float((int)(pk1 >> 32));
        float w2 = __int_as_float((int)(pk2 >> 32));
        float w3 = __int_as_float((int)(pk3 >> 32));
        float* a0 = &acc[((lo0 >> 17) & (BNODES - 1)) * CCH + l3];
        float* a1 = &acc[((lo1 >> 17) & (BNODES - 1)) * CCH + l3];
        float* a2 = &acc[((lo2 >> 17) & (BNODES - 1)) * CCH + l3];
        float* a3 = &acc[((lo3 >> 17) & (BNODES - 1)) * CCH + l3];
        atomicAdd(a0, w0 * x0); atomicAdd(a0 + 1, w0 * y0); atomicAdd(a0 + 2, w0 * z0);
        atomicAdd(a1, w1 * x1); atomicAdd(a1 + 1, w1 * y1); atomicAdd(a1 + 2, w1 * z1);
        atomicAdd(a2, w2 * x2); atomicAdd(a2 + 1, w2 * y2); atomicAdd(a2 + 2, w2 * z2);
        atomicAdd(a3, w3 * x3); atomicAdd(a3 + 1, w3 * y3); atomicAdd(a3 + 2, w3 * z3);
    }
    for (; i < end; i += 16) {
        unsigned long long pk = binned[i];
        int lo = (int)pk;
        float w = __int_as_float((int)(pk >> 32));
        const float* p = label + (long long)(lo & 0x1FFFF) * CCH + l3;
        float* a = &acc[((lo >> 17) & (BNODES - 1)) * CCH + l3];
        atomicAdd(a, w * p[0]); atomicAdd(a + 1, w * p[1]); atomicAdd(a + 2, w * p[2]);
    }
    __syncthreads();

    int n0 = b << SHIFT;
    for (int j = tid; j < BNODES * CCH; j += 256) {
        int ln = j / CCH;
        int c  = j - ln * CCH;
        int n  = n0 + ln;
        if (n < N) {
            float dn = dis[n];
            long long idx = (long long)n * CCH + c;
            out[idx] = dn * (acc[j] + dn * label[idx]);
        }
    }
}

extern "C" void kernel_launch(void* const* d_in, const int* in_sizes, int n_in,
                              void* d_out, int out_size, void* d_ws, size_t ws_size,
                              hipStream_t stream) {
    const float* label = (const float*)d_in[0];  // fp32 (N,48)
    const int* ei = (const int*)d_in[1];         // int32, (2,E) flat

    const int NC = in_sizes[0];  // N * 48
    const int N  = NC / CCH;
    const int E  = in_sizes[1] / 2;
    const int* row = ei;
    const int* col = ei + E;

    const int NB  = (N + BNODES - 1) >> SHIFT;       // 3125 buckets
    const int NB1 = (E + EPB - 1) / EPB;             // 391 binning blocks
    const int M   = NB * NB1;                        // ~1.22M scan entries
    const int B   = (M + TILE - 1) / TILE;           // ~597 scan blocks

    // ws layout: [binned: E u64][degR: RREP*N i32][dis: N f32]
    //            [table: M i32][scanOut: M+1 i32][bsum: B][boff: B]
    unsigned long long* binned = (unsigned long long*)d_ws;
    int* degR = (int*)(binned + E);
    float* dis = (float*)(degR + (long long)RREP * N);
    int* table = (int*)(dis + N);
    int* scanOut = table + M;
    int* bsum = scanOut + (M + 1);
    int* boff = bsum + B;

    // Zero degR only; everything else is fully written before read.
    hipMemsetAsync(degR, 0, (size_t)RREP * N * sizeof(int), stream);

    histo_deg<<<(E + 255) / 256, 256, 0, stream>>>(row, degR, N, E);
    reduce_dis<<<(N + 255) / 256, 256, 0, stream>>>(degR, dis, N);

    bin_count<<<NB1, 256, 0, stream>>>(col, table, E, NB, NB1);
    scan_partial<<<B, SBT, 0, stream>>>(table, bsum, M);
    scan_block<<<1, 1024, 0, stream>>>(bsum, boff, scanOut, B, M, E);
    scan_final<<<B, SBT, 0, stream>>>(table, boff, scanOut, M);

    bin_scatter<<<NB1, 256, 0, stream>>>(row, col, dis, scanOut, binned, E, NB, NB1);

    bucket_gather<<<NB, 256, 0, stream>>>(label, binned, scanOut, dis,
                                          (float*)d_out, N, NB1);
}

// Round 10
// 371.074 us; speedup vs baseline: 1.8786x; 1.6596x over previous
//
#include <hip/hip_runtime.h>

#define CCH 48       // channels
#define R 16         // histogram/counter replicas
#define TILE 2048    // scan elements per block (8/thread)
#define SBT 256      // scan block threads

// --- Pass 1: col-count histogram, replicated, 4 edges/thread (int4, ILP) ---
__global__ void histo_cnt(const int* __restrict__ col, int* __restrict__ cntR,
                          int N, int E) {
    int t = blockIdx.x * blockDim.x + threadIdx.x;
    int e0 = t * 4;
    long long r = blockIdx.x & (R - 1);
    int* base = cntR + r * N;
    if (e0 + 3 < E) {
        int4 c = *reinterpret_cast<const int4*>(col + e0);
        atomicAdd(base + c.x, 1);
        atomicAdd(base + c.y, 1);
        atomicAdd(base + c.z, 1);
        atomicAdd(base + c.w, 1);
    } else {
        for (int k = 0; k < 4; ++k) {
            int e = e0 + k;
            if (e < E) atomicAdd(base + col[e], 1);
        }
    }
}

// --- 3-pass scan over logical order j = n*R + r  ->  curR (replica-major), ptrB ---
static __device__ __forceinline__ int cnt_at(const int* __restrict__ cntR, int N, int M, int j) {
    if (j >= M) return 0;
    int r = j & (R - 1);
    int n = j >> 4;
    return cntR[(long long)r * N + n];
}

__global__ void __launch_bounds__(SBT) scan_partial(const int* __restrict__ cntR,
                                                    int* __restrict__ bsum, int N, int M) {
    __shared__ int sm[SBT];
    int b = blockIdx.x, tid = threadIdx.x;
    int base = b * TILE + tid * 8;
    int s = 0;
#pragma unroll
    for (int k = 0; k < 8; ++k) s += cnt_at(cntR, N, M, base + k);
    sm[tid] = s;
    __syncthreads();
    for (int off = SBT / 2; off > 0; off >>= 1) {
        if (tid < off) sm[tid] += sm[tid + off];
        __syncthreads();
    }
    if (tid == 0) bsum[b] = sm[0];
}

__global__ void __launch_bounds__(1024) scan_block(const int* __restrict__ bsum,
                                                   int* __restrict__ boff,
                                                   int* __restrict__ ptrB,
                                                   int B, int N, int E) {
    __shared__ int sm[1024];
    int tid = threadIdx.x;
    int v = (tid < B) ? bsum[tid] : 0;
    sm[tid] = v;
    __syncthreads();
    for (int off = 1; off < 1024; off <<= 1) {
        int t = (tid >= off) ? sm[tid - off] : 0;
        __syncthreads();
        sm[tid] += t;
        __syncthreads();
    }
    if (tid < B) boff[tid] = sm[tid] - v;
    if (tid == 0) ptrB[N] = E;  // sentinel
}

__global__ void __launch_bounds__(SBT) scan_final(const int* __restrict__ cntR,
                                                  const int* __restrict__ boff,
                                                  int* __restrict__ ptrB,
                                                  int* __restrict__ curR, int N, int M) {
    __shared__ int sm[SBT];
    int b = blockIdx.x, tid = threadIdx.x;
    int base = b * TILE + tid * 8;
    int v[8];
    int s = 0;
#pragma unroll
    for (int k = 0; k < 8; ++k) { v[k] = cnt_at(cntR, N, M, base + k); s += v[k]; }
    sm[tid] = s;
    __syncthreads();
    for (int off = 1; off < SBT; off <<= 1) {
        int t = (tid >= off) ? sm[tid - off] : 0;
        __syncthreads();
        sm[tid] += t;
        __syncthreads();
    }
    int run = boff[b] + sm[tid] - s;
#pragma unroll
    for (int k = 0; k < 8; ++k) {
        int j = base + k;
        if (j < M) {
            int r = j & (R - 1);
            int n = j >> 4;
            curR[(long long)r * N + n] = run;
            if (r == 0) ptrB[n] = run;
        }
        run += v[k];
    }
}

// --- Pass 2: CSR fill + fused row-degree atomics, 4 edges/thread (int4) ---
__global__ void fill_deg(const int* __restrict__ row, const int* __restrict__ col,
                         int* __restrict__ curR, int* __restrict__ degR,
                         int* __restrict__ srcA, int N, int E) {
    int t = blockIdx.x * blockDim.x + threadIdx.x;
    int e0 = t * 4;
    long long r = blockIdx.x & (R - 1);
    int* cbase = curR + r * N;
    int* dbase = degR + r * N;
    if (e0 + 3 < E) {
        int4 rw = *reinterpret_cast<const int4*>(row + e0);
        int4 cl = *reinterpret_cast<const int4*>(col + e0);
        atomicAdd(dbase + rw.x, 1);
        atomicAdd(dbase + rw.y, 1);
        atomicAdd(dbase + rw.z, 1);
        atomicAdd(dbase + rw.w, 1);
        int p0 = atomicAdd(cbase + cl.x, 1);
        int p1 = atomicAdd(cbase + cl.y, 1);
        int p2 = atomicAdd(cbase + cl.z, 1);
        int p3 = atomicAdd(cbase + cl.w, 1);
        srcA[p0] = rw.x;
        srcA[p1] = rw.y;
        srcA[p2] = rw.z;
        srcA[p3] = rw.w;
    } else {
        for (int k = 0; k < 4; ++k) {
            int e = e0 + k;
            if (e < E) {
                int rwk = row[e];
                atomicAdd(dbase + rwk, 1);
                int p = atomicAdd(cbase + col[e], 1);
                srcA[p] = rwk;
            }
        }
    }
}

// dis[n] = rsqrt(sum_r degR[r*N+n] + 1)
__global__ void reduce_dis(const int* __restrict__ degR, float* __restrict__ dis, int N) {
    int n = blockIdx.x * blockDim.x + threadIdx.x;
    if (n >= N) return;
    int s = 0;
#pragma unroll
    for (int r = 0; r < R; ++r) s += degR[(long long)r * N + n];
    dis[n] = rsqrtf((float)s + 1.0f);
}

// --- Gather: 8 lanes/node, 6 channels/lane, 2-edge unrolled pipeline ---
// out[n,c] = dis[n] * ( sum_{e: col=n} dis[src]*label[src,c] + dis[n]*label[n,c] )
__global__ void gather(const float* __restrict__ label,
                       const int* __restrict__ ptrB,
                       const int* __restrict__ srcA,
                       const float* __restrict__ dis,
                       float* __restrict__ out, int N) {
    int t = blockIdx.x * blockDim.x + threadIdx.x;
    int n = t >> 3;
    if (n >= N) return;
    int c0 = (t & 7) * 6;
    int beg = ptrB[n], end = ptrB[n + 1];
    float a0 = 0.f, a1 = 0.f, a2 = 0.f, a3 = 0.f, a4 = 0.f, a5 = 0.f;
    int i = beg;
    for (; i + 2 <= end; i += 2) {
        int s0 = srcA[i], s1 = srcA[i + 1];
        float w0 = dis[s0], w1 = dis[s1];
        const float* p0 = label + (long long)s0 * CCH + c0;
        const float* p1 = label + (long long)s1 * CCH + c0;
        float2 u0 = *reinterpret_cast<const float2*>(p0);
        float2 u1 = *reinterpret_cast<const float2*>(p0 + 2);
        float2 u2 = *reinterpret_cast<const float2*>(p0 + 4);
        float2 v0 = *reinterpret_cast<const float2*>(p1);
        float2 v1 = *reinterpret_cast<const float2*>(p1 + 2);
        float2 v2 = *reinterpret_cast<const float2*>(p1 + 4);
        a0 += w0 * u0.x; a1 += w0 * u0.y; a2 += w0 * u1.x;
        a3 += w0 * u1.y; a4 += w0 * u2.x; a5 += w0 * u2.y;
        a0 += w1 * v0.x; a1 += w1 * v0.y; a2 += w1 * v1.x;
        a3 += w1 * v1.y; a4 += w1 * v2.x; a5 += w1 * v2.y;
    }
    if (i < end) {
        int s0 = srcA[i];
        float w0 = dis[s0];
        const float* p0 = label + (long long)s0 * CCH + c0;
        float2 u0 = *reinterpret_cast<const float2*>(p0);
        float2 u1 = *reinterpret_cast<const float2*>(p0 + 2);
        float2 u2 = *reinterpret_cast<const float2*>(p0 + 4);
        a0 += w0 * u0.x; a1 += w0 * u0.y; a2 += w0 * u1.x;
        a3 += w0 * u1.y; a4 += w0 * u2.x; a5 += w0 * u2.y;
    }
    float dn = dis[n];
    const float* q = label + (long long)n * CCH + c0;
    float* o = out + (long long)n * CCH + c0;
    o[0] = dn * (a0 + dn * q[0]);
    o[1] = dn * (a1 + dn * q[1]);
    o[2] = dn * (a2 + dn * q[2]);
    o[3] = dn * (a3 + dn * q[3]);
    o[4] = dn * (a4 + dn * q[4]);
    o[5] = dn * (a5 + dn * q[5]);
}

extern "C" void kernel_launch(void* const* d_in, const int* in_sizes, int n_in,
                              void* d_out, int out_size, void* d_ws, size_t ws_size,
                              hipStream_t stream) {
    const float* label = (const float*)d_in[0];  // fp32 (N,48)
    const int* ei = (const int*)d_in[1];         // int32, (2,E) flat

    const int NC = in_sizes[0];  // N * 48
    const int N  = NC / CCH;
    const int E  = in_sizes[1] / 2;
    const int* row = ei;
    const int* col = ei + E;

    const int M = R * N;                    // logical scan length (1.6M)
    const int B = (M + TILE - 1) / TILE;    // scan blocks (782)

    // ws layout (all int32-sized):
    // [degR: R*N][cntR: R*N][curR: R*N][ptrB: N+1][dis: N f32][srcA: E][bsum: B][boff: B]
    int* degR = (int*)d_ws;
    int* cntR = degR + (long long)M;
    int* curR = cntR + (long long)M;
    int* ptrB = curR + (long long)M;
    float* dis = (float*)(ptrB + (N + 1));
    int* srcA = (int*)(dis + N);
    int* bsum = srcA + E;
    int* boff = bsum + B;

    // Zero degR + cntR (contiguous 2*R*N ints). Everything else fully written.
    hipMemsetAsync(d_ws, 0, (size_t)(2LL * M) * sizeof(int), stream);

    int quads = (E + 3) / 4;
    histo_cnt<<<(quads + 255) / 256, 256, 0, stream>>>(col, cntR, N, E);

    scan_partial<<<B, SBT, 0, stream>>>(cntR, bsum, N, M);
    scan_block<<<1, 1024, 0, stream>>>(bsum, boff, ptrB, B, N, E);
    scan_final<<<B, SBT, 0, stream>>>(cntR, boff, ptrB, curR, N, M);

    fill_deg<<<(quads + 255) / 256, 256, 0, stream>>>(row, col, curR, degR, srcA, N, E);
    reduce_dis<<<(N + 255) / 256, 256, 0, stream>>>(degR, dis, N);

    int tg = N * 8;
    gather<<<(tg + 255) / 256, 256, 0, stream>>>(label, ptrB, srcA, dis,
                                                 (float*)d_out, N);
}